// Round 1
// baseline (2378.623 us; speedup 1.0000x reference)
//
#include <hip/hip_runtime.h>

typedef unsigned short u16;
typedef __attribute__((ext_vector_type(8))) __bf16 bf16x8;
typedef __attribute__((ext_vector_type(4))) float f32x4;

__device__ __forceinline__ float bf2f(u16 u) {
    return __uint_as_float(((unsigned int)u) << 16);
}
__device__ __forceinline__ u16 f2bf(float f) {
    unsigned int u = __float_as_uint(f);
    u += 0x7fffu + ((u >> 16) & 1u);   // round-to-nearest-even
    return (u16)(u >> 16);
}

// ---------------------------------------------------------------------------
// f32 -> bf16 convert (weights)
// ---------------------------------------------------------------------------
__global__ __launch_bounds__(256) void cvt_bf16(const float* __restrict__ in,
                                                u16* __restrict__ out, int n) {
    int tid = blockIdx.x * 256 + threadIdx.x;
    if (tid < n) out[tid] = f2bf(in[tid]);
}

// ---------------------------------------------------------------------------
// Depthwise 3x3x3 conv positional embedding.  resid (=d_out) gets xpe.
// x: [1569, 8, 1024]; token r = (i*14+j)*8 + t; resid fully written.
// ---------------------------------------------------------------------------
__global__ __launch_bounds__(256) void posembed(const float* __restrict__ x,
                                                const float* __restrict__ w,
                                                const float* __restrict__ pb,
                                                float* __restrict__ out) {
    int tid = blockIdx.x * 256 + threadIdx.x;   // exactly 1569*8192 threads
    float xv = x[tid];
    int c = tid & 1023;
    int rf = tid >> 13;
    if (rf == 0) { out[tid] = xv; return; }
    int n = (tid >> 10) & 7;
    int r = rf - 1;
    int t = r & 7, l = r >> 3;
    int i = l / 14, j = l - i * 14;
    float acc = xv + pb[c];
    const float* wc = w + c * 27;
#pragma unroll
    for (int dt = 0; dt < 3; dt++) {
        int tt = t + dt - 1;
        if (tt < 0 || tt > 7) continue;
#pragma unroll
        for (int di = 0; di < 3; di++) {
            int ii = i + di - 1;
            if (ii < 0 || ii > 13) continue;
#pragma unroll
            for (int dj = 0; dj < 3; dj++) {
                int jj = j + dj - 1;
                if (jj < 0 || jj > 13) continue;
                size_t src = (size_t)(1 + ((ii * 14 + jj) << 3) + tt) * 8192 + (n << 10) + c;
                acc += wc[dt * 9 + di * 3 + dj] * x[src];
            }
        }
    }
    out[tid] = acc;
}

// ---------------------------------------------------------------------------
// LayerNorm with branch-specific row gather, f32 in -> bf16 out.
// mode 0: temporal  row ro = t*1568 + n*196 + l   <- resid[1 + l*8 + t, n]
// mode 1: spatial   row ro = s*64 + t*8 + n       <- resid[0,n] (s=0) or
//                   resid[1+(s-1)*8+t, n] + Radd[t*1568+n*196+(s-1)]  (fused xt_full)
// mode 2: mlp       row ro = r*8 + n              <- resid[r, n]
// ---------------------------------------------------------------------------
__global__ __launch_bounds__(256) void ln_kernel(const float* __restrict__ resid,
                                                 const u16* __restrict__ Radd,
                                                 const float* __restrict__ g,
                                                 const float* __restrict__ bb,
                                                 u16* __restrict__ out, int mode) {
    int ro = blockIdx.x;
    int tid = threadIdx.x;
    int src, n;
    long long rarow = -1;
    if (mode == 0) {
        int t = ro / 1568, b2 = ro - t * 1568;
        n = b2 / 196;
        int l = b2 - n * 196;
        src = 1 + l * 8 + t;
    } else if (mode == 1) {
        int s = ro >> 6, u = ro & 63;
        int t = u >> 3;
        n = u & 7;
        if (s == 0) src = 0;
        else { src = 1 + (s - 1) * 8 + t; rarow = (long long)(t * 1568 + n * 196 + (s - 1)); }
    } else {
        src = ro >> 3;
        n = ro & 7;
    }
    const float* xp = resid + ((size_t)src * 8 + n) * 1024 + tid * 4;
    float4 xv = *(const float4*)xp;
    float x0 = xv.x, x1 = xv.y, x2 = xv.z, x3 = xv.w;
    if (rarow >= 0) {
        const u16* rp = Radd + rarow * 1024 + tid * 4;
        x0 += bf2f(rp[0]); x1 += bf2f(rp[1]); x2 += bf2f(rp[2]); x3 += bf2f(rp[3]);
    }
    float s1 = x0 + x1 + x2 + x3;
    float s2 = x0 * x0 + x1 * x1 + x2 * x2 + x3 * x3;
#pragma unroll
    for (int off = 32; off > 0; off >>= 1) {
        s1 += __shfl_down(s1, off);
        s2 += __shfl_down(s2, off);
    }
    __shared__ float red[8];
    int lane = tid & 63, w = tid >> 6;
    if (lane == 0) { red[w] = s1; red[4 + w] = s2; }
    __syncthreads();
    float S1 = red[0] + red[1] + red[2] + red[3];
    float S2 = red[4] + red[5] + red[6] + red[7];
    float mean = S1 * (1.f / 1024.f);
    float var = S2 * (1.f / 1024.f) - mean * mean;
    float rstd = rsqrtf(var + 1e-5f);
    int c = tid * 4;
    u16* op = out + (size_t)ro * 1024 + c;
    op[0] = f2bf((x0 - mean) * rstd * g[c + 0] + bb[c + 0]);
    op[1] = f2bf((x1 - mean) * rstd * g[c + 1] + bb[c + 1]);
    op[2] = f2bf((x2 - mean) * rstd * g[c + 2] + bb[c + 2]);
    op[3] = f2bf((x3 - mean) * rstd * g[c + 3] + bb[c + 3]);
}

// ---------------------------------------------------------------------------
// bf16 MFMA GEMM:  C[M,N] = epi(A[M,K] @ W[N,K]^T + bias[N]),  bf16 out.
// 128x128 tile, BK=32, 4 waves each computing a 64x64 quadrant (4x4 subtiles).
// N must be a multiple of 128; M rows clamped/guarded.
// ---------------------------------------------------------------------------
__global__ __launch_bounds__(256) void gemm_bf16(const u16* __restrict__ A,
                                                 const u16* __restrict__ W,
                                                 const float* __restrict__ bias,
                                                 u16* __restrict__ Co,
                                                 int M, int N, int K, int gelu) {
    __shared__ u16 As[128 * 32];
    __shared__ u16 Bs[128 * 32];
    int tid = threadIdx.x;
    int n0 = blockIdx.x * 128, m0 = blockIdx.y * 128;
    int lane = tid & 63, wid = tid >> 6;
    int wm = (wid >> 1) * 64, wn = (wid & 1) * 64;
    int lm = lane & 15, q = lane >> 4;

    f32x4 acc[4][4];
#pragma unroll
    for (int i = 0; i < 4; i++)
#pragma unroll
        for (int j = 0; j < 4; j++) acc[i][j] = (f32x4){0.f, 0.f, 0.f, 0.f};

    int sr = tid >> 1;
    int ac = (tid & 1) * 16;
    int ar = m0 + sr;
    if (ar > M - 1) ar = M - 1;                  // clamp (stores guarded later)
    const u16* Ap = A + (size_t)ar * K + ac;
    const u16* Wp = W + (size_t)(n0 + sr) * K + ac;
    u16* AsP = &As[sr * 32 + ac];
    u16* BsP = &Bs[sr * 32 + ac];

    for (int k0 = 0; k0 < K; k0 += 32) {
        uint4 a0 = *(const uint4*)(Ap);
        uint4 a1 = *(const uint4*)(Ap + 8);
        uint4 b0 = *(const uint4*)(Wp);
        uint4 b1 = *(const uint4*)(Wp + 8);
        Ap += 32; Wp += 32;
        __syncthreads();
        *(uint4*)AsP = a0; *(uint4*)(AsP + 8) = a1;
        *(uint4*)BsP = b0; *(uint4*)(BsP + 8) = b1;
        __syncthreads();
        bf16x8 af[4], bfr[4];
#pragma unroll
        for (int i = 0; i < 4; i++) af[i] = *(const bf16x8*)&As[(wm + i * 16 + lm) * 32 + q * 8];
#pragma unroll
        for (int j = 0; j < 4; j++) bfr[j] = *(const bf16x8*)&Bs[(wn + j * 16 + lm) * 32 + q * 8];
#pragma unroll
        for (int i = 0; i < 4; i++)
#pragma unroll
            for (int j = 0; j < 4; j++)
                acc[i][j] = __builtin_amdgcn_mfma_f32_16x16x32_bf16(af[i], bfr[j], acc[i][j], 0, 0, 0);
    }

#pragma unroll
    for (int i = 0; i < 4; i++) {
        int row_b = m0 + wm + i * 16 + q * 4;
#pragma unroll
        for (int j = 0; j < 4; j++) {
            int col = n0 + wn + j * 16 + lm;
            float bv = bias[col];
#pragma unroll
            for (int r = 0; r < 4; r++) {
                int row = row_b + r;
                if (row < M) {
                    float v = acc[i][j][r] + bv;
                    if (gelu) v = v / (1.f + __expf(-1.702f * v));  // QuickGELU
                    Co[(size_t)row * N + col] = f2bf(v);
                }
            }
        }
    }
}

// ---------------------------------------------------------------------------
// Temporal attention: S=8, one wave per (b, h).  qkv rows: t*1568 + b,
// cols [q|k|v] at {0,1024,2048} + h*64 + d.  Out rows t*1568 + b, col h*64+d.
// bias = rpb_t[tq - tk + 7, h].
// ---------------------------------------------------------------------------
__global__ __launch_bounds__(64) void attn_t(const u16* __restrict__ qkv,
                                             const float* __restrict__ rpb,
                                             u16* __restrict__ out) {
    int blk = blockIdx.x;
    int b = blk % 1568, h = blk / 1568;
    int d = threadIdx.x;
    __shared__ float qs[8][65], ks[8][65], vs[8][65];
    __shared__ float ps[8][9];
#pragma unroll
    for (int t = 0; t < 8; t++) {
        size_t row = (size_t)(t * 1568 + b) * 3072 + h * 64 + d;
        qs[t][d] = bf2f(qkv[row]) * 0.125f;
        ks[t][d] = bf2f(qkv[row + 1024]);
        vs[t][d] = bf2f(qkv[row + 2048]);
    }
    __syncthreads();
    int tq = d >> 3, tk = d & 7;
    float s = rpb[(tq - tk + 7) * 16 + h];
#pragma unroll
    for (int dd = 0; dd < 64; dd++) s += qs[tq][dd] * ks[tk][dd];
    float mx = s;
    mx = fmaxf(mx, __shfl_xor(mx, 1));
    mx = fmaxf(mx, __shfl_xor(mx, 2));
    mx = fmaxf(mx, __shfl_xor(mx, 4));
    float p = __expf(s - mx);
    float su = p;
    su += __shfl_xor(su, 1);
    su += __shfl_xor(su, 2);
    su += __shfl_xor(su, 4);
    ps[tq][tk] = p / su;
    __syncthreads();
#pragma unroll
    for (int t2 = 0; t2 < 8; t2++) {
        float o = 0.f;
#pragma unroll
        for (int k2 = 0; k2 < 8; k2++) o += ps[t2][k2] * vs[k2][d];
        out[(size_t)(t2 * 1568 + b) * 1024 + h * 64 + d] = f2bf(o);
    }
}

// ---------------------------------------------------------------------------
// Spatial attention: S'=197 (cls + 196), B'=64 (u = t*8+n), one block(256)
// per (u, h).  K^T and V staged in LDS as bf16; 4 waves sweep q rows.
// bias = rpb_s[(qi-ki+13)*27 + (qj-kj+13), h] for q,k >= 1 else 0.
// ---------------------------------------------------------------------------
#define SKT 208
__global__ __launch_bounds__(256) void attn_s(const u16* __restrict__ qkv,
                                              const float* __restrict__ rpb,
                                              u16* __restrict__ out) {
    int blk = blockIdx.x;
    int u = blk & 63, h = blk >> 6;
    __shared__ u16 KT[64 * SKT + 64];   // [d][tk], padded for safe OOB reads
    __shared__ u16 V[197 * 64];         // [tk][d]
    __shared__ float qbuf[4][64];
    __shared__ float pbuf[4][SKT];
    int tid = threadIdx.x;
    for (int idx = tid; idx < 197 * 64; idx += 256) {
        int s = idx >> 6, d = idx & 63;
        size_t row = (size_t)(s * 64 + u) * 3072 + h * 64 + d;
        KT[d * SKT + s] = qkv[row + 1024];
        V[idx] = qkv[row + 2048];
    }
    __syncthreads();
    int w = tid >> 6, lane = tid & 63;
    for (int it = 0; it < 50; ++it) {
        int qr = it * 4 + w;
        bool act = qr < 197;
        if (act) qbuf[w][lane] = bf2f(qkv[(size_t)(qr * 64 + u) * 3072 + h * 64 + lane]) * 0.125f;
        __syncthreads();
        if (act) {
            float s0 = 0.f, sA = 0.f, sB = 0.f, sC = 0.f;
            for (int dd = 0; dd < 64; dd++) {
                float qv = qbuf[w][dd];
                const u16* kp = &KT[dd * SKT + lane];
                s0 += qv * bf2f(kp[0]);
                sA += qv * bf2f(kp[64]);
                sB += qv * bf2f(kp[128]);
                sC += qv * bf2f(kp[192]);
            }
            float s[4] = {s0, sA, sB, sC};
            int lq = qr - 1;
            int qi = lq / 14, qj = lq - qi * 14;
#pragma unroll
            for (int m = 0; m < 4; m++) {
                int tk = lane + 64 * m;
                if (tk >= 197) { s[m] = -1e30f; continue; }
                if (qr >= 1 && tk >= 1) {
                    int lk = tk - 1;
                    int ki = lk / 14, kj = lk - ki * 14;
                    s[m] += rpb[((qi - ki + 13) * 27 + (qj - kj + 13)) * 16 + h];
                }
            }
            float mx = fmaxf(fmaxf(s[0], s[1]), fmaxf(s[2], s[3]));
#pragma unroll
            for (int off = 1; off < 64; off <<= 1) mx = fmaxf(mx, __shfl_xor(mx, off));
            float psum = 0.f;
#pragma unroll
            for (int m = 0; m < 4; m++) {
                int tk = lane + 64 * m;
                float p = __expf(s[m] - mx);
                if (tk < 197) { pbuf[w][tk] = p; psum += p; }
            }
#pragma unroll
            for (int off = 1; off < 64; off <<= 1) psum += __shfl_xor(psum, off);
            float o = 0.f;
            for (int tk = 0; tk < 197; tk++) o += pbuf[w][tk] * bf2f(V[tk * 64 + lane]);
            out[(size_t)(qr * 64 + u) * 1024 + h * 64 + lane] = f2bf(o / psum);
        }
    }
}

// ---------------------------------------------------------------------------
// Residual adds
// ---------------------------------------------------------------------------
__global__ __launch_bounds__(256) void add_cls(const u16* __restrict__ R, float* __restrict__ resid) {
    int tid = blockIdx.x * 256 + threadIdx.x;   // 8192
    int c = tid & 1023, n = tid >> 10;
    float s = 0.f;
#pragma unroll
    for (int t = 0; t < 8; t++) s += bf2f(R[(size_t)(t * 8 + n) * 1024 + c]);
    resid[tid] += s * 0.125f;
}

__global__ __launch_bounds__(256) void add_spa(const u16* __restrict__ R, float* __restrict__ resid) {
    int tid = blockIdx.x * 256 + threadIdx.x;   // 1568*8192
    int c = tid & 1023;
    int n = (tid >> 10) & 7;
    int r = tid >> 13;
    int t = r & 7, l = r >> 3;
    int srow = (l + 1) * 64 + t * 8 + n;
    resid[tid + 8192] += bf2f(R[(size_t)srow * 1024 + c]);
}

__global__ __launch_bounds__(256) void add_flat(const u16* __restrict__ R, float* __restrict__ resid) {
    int tid = blockIdx.x * 256 + threadIdx.x;   // 12552*1024
    resid[tid] += bf2f(R[tid]);
}

// ---------------------------------------------------------------------------
extern "C" void kernel_launch(void* const* d_in, const int* in_sizes, int n_in,
                              void* d_out, int out_size, void* d_ws, size_t ws_size,
                              hipStream_t stream) {
    const float* x      = (const float*)d_in[0];
    const float* pos_w  = (const float*)d_in[1];
    const float* pos_b  = (const float*)d_in[2];
    const float* ln_t_g = (const float*)d_in[3];
    const float* ln_t_b = (const float*)d_in[4];
    const float* rpb_t  = (const float*)d_in[5];
    const float* wqkv_t = (const float*)d_in[6];
    const float* bqkv_t = (const float*)d_in[7];
    const float* wo_t   = (const float*)d_in[8];
    const float* bo_t   = (const float*)d_in[9];
    const float* ln1_g  = (const float*)d_in[10];
    const float* ln1_b  = (const float*)d_in[11];
    const float* rpb_s  = (const float*)d_in[12];
    const float* wqkv_s = (const float*)d_in[13];
    const float* bqkv_s = (const float*)d_in[14];
    const float* wo_s   = (const float*)d_in[15];
    const float* bo_s   = (const float*)d_in[16];
    const float* ln2_g  = (const float*)d_in[17];
    const float* ln2_b  = (const float*)d_in[18];
    const float* fc_w   = (const float*)d_in[19];
    const float* fc_b   = (const float*)d_in[20];
    const float* proj_w = (const float*)d_in[21];
    const float* proj_b = (const float*)d_in[22];
    float* resid = (float*)d_out;

    // workspace arena (bf16 elements)
    u16* Wq_t  = (u16*)d_ws;
    u16* Wo_t  = Wq_t + 3145728;
    u16* Wq_s  = Wo_t + 1048576;
    u16* Wo_s  = Wq_s + 3145728;
    u16* Wfc   = Wo_s + 1048576;
    u16* Wpj   = Wfc  + 4194304;
    u16* Albuf = Wpj  + 4194304;          // 12608*1024
    u16* QKV   = Albuf + 12910592;        // 12608*3072
    u16* Obuf  = QKV   + 38731776;        // 12608*1024
    u16* Rbuf  = Obuf  + 12910592;        // 12608*1024
    u16* Hbuf  = QKV;                     // alias: 12552*4096 fits in QKV+Obuf

    // weight conversion
    cvt_bf16<<<12288, 256, 0, stream>>>(wqkv_t, Wq_t, 3145728);
    cvt_bf16<<<4096,  256, 0, stream>>>(wo_t,   Wo_t, 1048576);
    cvt_bf16<<<12288, 256, 0, stream>>>(wqkv_s, Wq_s, 3145728);
    cvt_bf16<<<4096,  256, 0, stream>>>(wo_s,   Wo_s, 1048576);
    cvt_bf16<<<16384, 256, 0, stream>>>(fc_w,   Wfc,  4194304);
    cvt_bf16<<<16384, 256, 0, stream>>>(proj_w, Wpj,  4194304);

    // positional embedding -> resid (= xpe)
    posembed<<<50208, 256, 0, stream>>>(x, pos_w, pos_b, resid);

    // temporal attention (result NOT added to resid; feeds spatial LN only)
    ln_kernel<<<12544, 256, 0, stream>>>(resid, nullptr, ln_t_g, ln_t_b, Albuf, 0);
    gemm_bf16<<<dim3(24, 98), 256, 0, stream>>>(Albuf, Wq_t, bqkv_t, QKV, 12544, 3072, 1024, 0);
    attn_t<<<25088, 64, 0, stream>>>(QKV, rpb_t, Obuf);
    gemm_bf16<<<dim3(8, 98), 256, 0, stream>>>(Obuf, Wo_t, bo_t, Rbuf, 12544, 1024, 1024, 0);

    // spatial attention (LN1 fuses xt_full = xpe + rt gather)
    ln_kernel<<<12608, 256, 0, stream>>>(resid, Rbuf, ln1_g, ln1_b, Albuf, 1);
    gemm_bf16<<<dim3(24, 99), 256, 0, stream>>>(Albuf, Wq_s, bqkv_s, QKV, 12608, 3072, 1024, 0);
    attn_s<<<1024, 256, 0, stream>>>(QKV, rpb_s, Obuf);
    gemm_bf16<<<dim3(8, 99), 256, 0, stream>>>(Obuf, Wo_s, bo_s, Rbuf, 12608, 1024, 1024, 0);
    add_cls<<<32, 256, 0, stream>>>(Rbuf, resid);
    add_spa<<<50176, 256, 0, stream>>>(Rbuf, resid);

    // MLP with QuickGELU
    ln_kernel<<<12552, 256, 0, stream>>>(resid, nullptr, ln2_g, ln2_b, Albuf, 2);
    gemm_bf16<<<dim3(32, 99), 256, 0, stream>>>(Albuf, Wfc, fc_b, Hbuf, 12552, 4096, 1024, 1);
    gemm_bf16<<<dim3(8, 99), 256, 0, stream>>>(Hbuf, Wpj, proj_b, Rbuf, 12552, 1024, 4096, 0);
    add_flat<<<50208, 256, 0, stream>>>(Rbuf, resid);
}

// Round 2
// 1663.012 us; speedup vs baseline: 1.4303x; 1.4303x over previous
//
#include <hip/hip_runtime.h>
#include <stdint.h>

typedef unsigned short u16;
typedef __attribute__((ext_vector_type(8))) __bf16 bf16x8;
typedef __attribute__((ext_vector_type(4))) float f32x4;

__device__ __forceinline__ float bf2f(u16 u) {
    return __uint_as_float(((unsigned int)u) << 16);
}
__device__ __forceinline__ u16 f2bf(float f) {
    unsigned int u = __float_as_uint(f);
    u += 0x7fffu + ((u >> 16) & 1u);   // round-to-nearest-even
    return (u16)(u >> 16);
}

// async global->LDS, 16B per lane.  LDS dest = wave-uniform base + lane*16.
__device__ __forceinline__ void gl16(const u16* g, u16* l) {
    __builtin_amdgcn_global_load_lds(
        (const __attribute__((address_space(1))) unsigned int*)(uintptr_t)g,
        (__attribute__((address_space(3))) unsigned int*)(uintptr_t)l,
        16, 0, 0);
}

// ---------------------------------------------------------------------------
// f32 -> bf16 convert (weights)
// ---------------------------------------------------------------------------
__global__ __launch_bounds__(256) void cvt_bf16(const float* __restrict__ in,
                                                u16* __restrict__ out, int n) {
    int tid = blockIdx.x * 256 + threadIdx.x;
    if (tid < n) out[tid] = f2bf(in[tid]);
}

// ---------------------------------------------------------------------------
// Depthwise 3x3x3 conv positional embedding.  resid (=d_out) gets xpe.
// ---------------------------------------------------------------------------
__global__ __launch_bounds__(256) void posembed(const float* __restrict__ x,
                                                const float* __restrict__ w,
                                                const float* __restrict__ pb,
                                                float* __restrict__ out) {
    int tid = blockIdx.x * 256 + threadIdx.x;   // exactly 1569*8192 threads
    float xv = x[tid];
    int c = tid & 1023;
    int rf = tid >> 13;
    if (rf == 0) { out[tid] = xv; return; }
    int n = (tid >> 10) & 7;
    int r = rf - 1;
    int t = r & 7, l = r >> 3;
    int i = l / 14, j = l - i * 14;
    float acc = xv + pb[c];
    const float* wc = w + c * 27;
#pragma unroll
    for (int dt = 0; dt < 3; dt++) {
        int tt = t + dt - 1;
        if (tt < 0 || tt > 7) continue;
#pragma unroll
        for (int di = 0; di < 3; di++) {
            int ii = i + di - 1;
            if (ii < 0 || ii > 13) continue;
#pragma unroll
            for (int dj = 0; dj < 3; dj++) {
                int jj = j + dj - 1;
                if (jj < 0 || jj > 13) continue;
                size_t src = (size_t)(1 + ((ii * 14 + jj) << 3) + tt) * 8192 + (n << 10) + c;
                acc += wc[dt * 9 + di * 3 + dj] * x[src];
            }
        }
    }
    out[tid] = acc;
}

// ---------------------------------------------------------------------------
// LayerNorm with branch-specific row gather, f32 in -> bf16 out.
// ---------------------------------------------------------------------------
__global__ __launch_bounds__(256) void ln_kernel(const float* __restrict__ resid,
                                                 const u16* __restrict__ Radd,
                                                 const float* __restrict__ g,
                                                 const float* __restrict__ bb,
                                                 u16* __restrict__ out, int mode) {
    int ro = blockIdx.x;
    int tid = threadIdx.x;
    int src, n;
    long long rarow = -1;
    if (mode == 0) {
        int t = ro / 1568, b2 = ro - t * 1568;
        n = b2 / 196;
        int l = b2 - n * 196;
        src = 1 + l * 8 + t;
    } else if (mode == 1) {
        int s = ro >> 6, u = ro & 63;
        int t = u >> 3;
        n = u & 7;
        if (s == 0) src = 0;
        else { src = 1 + (s - 1) * 8 + t; rarow = (long long)(t * 1568 + n * 196 + (s - 1)); }
    } else {
        src = ro >> 3;
        n = ro & 7;
    }
    const float* xp = resid + ((size_t)src * 8 + n) * 1024 + tid * 4;
    float4 xv = *(const float4*)xp;
    float x0 = xv.x, x1 = xv.y, x2 = xv.z, x3 = xv.w;
    if (rarow >= 0) {
        const u16* rp = Radd + rarow * 1024 + tid * 4;
        x0 += bf2f(rp[0]); x1 += bf2f(rp[1]); x2 += bf2f(rp[2]); x3 += bf2f(rp[3]);
    }
    float s1 = x0 + x1 + x2 + x3;
    float s2 = x0 * x0 + x1 * x1 + x2 * x2 + x3 * x3;
#pragma unroll
    for (int off = 32; off > 0; off >>= 1) {
        s1 += __shfl_down(s1, off);
        s2 += __shfl_down(s2, off);
    }
    __shared__ float red[8];
    int lane = tid & 63, w = tid >> 6;
    if (lane == 0) { red[w] = s1; red[4 + w] = s2; }
    __syncthreads();
    float S1 = red[0] + red[1] + red[2] + red[3];
    float S2 = red[4] + red[5] + red[6] + red[7];
    float mean = S1 * (1.f / 1024.f);
    float var = S2 * (1.f / 1024.f) - mean * mean;
    float rstd = rsqrtf(var + 1e-5f);
    int c = tid * 4;
    u16* op = out + (size_t)ro * 1024 + c;
    op[0] = f2bf((x0 - mean) * rstd * g[c + 0] + bb[c + 0]);
    op[1] = f2bf((x1 - mean) * rstd * g[c + 1] + bb[c + 1]);
    op[2] = f2bf((x2 - mean) * rstd * g[c + 2] + bb[c + 2]);
    op[3] = f2bf((x3 - mean) * rstd * g[c + 3] + bb[c + 3]);
}

// ---------------------------------------------------------------------------
// bf16 MFMA GEMM:  C[M,N] = epi(A[M,K] @ W[N,K]^T + bias[N]),  bf16 out.
// 128x128 tile, BK=32, global_load_lds width-16 staging (m97 pattern).
// ---------------------------------------------------------------------------
__global__ __launch_bounds__(256) void gemm_bf16(const u16* __restrict__ A,
                                                 const u16* __restrict__ W,
                                                 const float* __restrict__ bias,
                                                 u16* __restrict__ Co,
                                                 int M, int N, int K, int gelu) {
    __shared__ u16 As[128 * 32];
    __shared__ u16 Bs[128 * 32];
    int tid = threadIdx.x;
    int n0 = blockIdx.x * 128, m0 = blockIdx.y * 128;
    int lane = tid & 63, wid = tid >> 6;
    int wm = (wid >> 1) * 64, wn = (wid & 1) * 64;
    int lm = lane & 15, q = lane >> 4;

    f32x4 acc[4][4];
#pragma unroll
    for (int i = 0; i < 4; i++)
#pragma unroll
        for (int j = 0; j < 4; j++) acc[i][j] = (f32x4){0.f, 0.f, 0.f, 0.f};

    // staging map: wave w chunk c (c=0,1): lane l -> row w*32+c*16+(l>>2), col bf16 (l&3)*8
    int r0 = wid * 32 + (lane >> 2);
    int colb = (lane & 3) * 8;
    int mA0 = m0 + r0;          if (mA0 > M - 1) mA0 = M - 1;
    int mA1 = m0 + r0 + 16;     if (mA1 > M - 1) mA1 = M - 1;
    const u16* gA0 = A + (size_t)mA0 * K + colb;
    const u16* gA1 = A + (size_t)mA1 * K + colb;
    const u16* gB0 = W + (size_t)(n0 + r0) * K + colb;
    const u16* gB1 = W + (size_t)(n0 + r0 + 16) * K + colb;
    u16* lA0 = &As[wid * 1024];
    u16* lA1 = &As[wid * 1024 + 512];
    u16* lB0 = &Bs[wid * 1024];
    u16* lB1 = &Bs[wid * 1024 + 512];

    for (int k0 = 0; k0 < K; k0 += 32) {
        gl16(gA0, lA0); gl16(gA1, lA1);
        gl16(gB0, lB0); gl16(gB1, lB1);
        gA0 += 32; gA1 += 32; gB0 += 32; gB1 += 32;
        __syncthreads();              // drain vmcnt -> staged data visible
        bf16x8 af[4], bfr[4];
#pragma unroll
        for (int i = 0; i < 4; i++) af[i] = *(const bf16x8*)&As[(wm + i * 16 + lm) * 32 + q * 8];
#pragma unroll
        for (int j = 0; j < 4; j++) bfr[j] = *(const bf16x8*)&Bs[(wn + j * 16 + lm) * 32 + q * 8];
#pragma unroll
        for (int i = 0; i < 4; i++)
#pragma unroll
            for (int j = 0; j < 4; j++)
                acc[i][j] = __builtin_amdgcn_mfma_f32_16x16x32_bf16(af[i], bfr[j], acc[i][j], 0, 0, 0);
        __syncthreads();              // reads done before next overwrite
    }

#pragma unroll
    for (int i = 0; i < 4; i++) {
        int row_b = m0 + wm + i * 16 + q * 4;
#pragma unroll
        for (int j = 0; j < 4; j++) {
            int col = n0 + wn + j * 16 + lm;
            float bv = bias[col];
#pragma unroll
            for (int r = 0; r < 4; r++) {
                int row = row_b + r;
                if (row < M) {
                    float v = acc[i][j][r] + bv;
                    if (gelu) v = v / (1.f + __expf(-1.702f * v));  // QuickGELU
                    Co[(size_t)row * N + col] = f2bf(v);
                }
            }
        }
    }
}

// ---------------------------------------------------------------------------
// Temporal attention: S=8, one wave per (b, h).
// ---------------------------------------------------------------------------
__global__ __launch_bounds__(64) void attn_t(const u16* __restrict__ qkv,
                                             const float* __restrict__ rpb,
                                             u16* __restrict__ out) {
    int blk = blockIdx.x;
    int b = blk % 1568, h = blk / 1568;
    int d = threadIdx.x;
    __shared__ float qs[8][65], ks[8][65], vs[8][65];
    __shared__ float ps[8][9];
#pragma unroll
    for (int t = 0; t < 8; t++) {
        size_t row = (size_t)(t * 1568 + b) * 3072 + h * 64 + d;
        qs[t][d] = bf2f(qkv[row]) * 0.125f;
        ks[t][d] = bf2f(qkv[row + 1024]);
        vs[t][d] = bf2f(qkv[row + 2048]);
    }
    __syncthreads();
    int tq = d >> 3, tk = d & 7;
    float s = rpb[(tq - tk + 7) * 16 + h];
#pragma unroll
    for (int dd = 0; dd < 64; dd++) s += qs[tq][dd] * ks[tk][dd];
    float mx = s;
    mx = fmaxf(mx, __shfl_xor(mx, 1));
    mx = fmaxf(mx, __shfl_xor(mx, 2));
    mx = fmaxf(mx, __shfl_xor(mx, 4));
    float p = __expf(s - mx);
    float su = p;
    su += __shfl_xor(su, 1);
    su += __shfl_xor(su, 2);
    su += __shfl_xor(su, 4);
    ps[tq][tk] = p / su;
    __syncthreads();
#pragma unroll
    for (int t2 = 0; t2 < 8; t2++) {
        float o = 0.f;
#pragma unroll
        for (int k2 = 0; k2 < 8; k2++) o += ps[t2][k2] * vs[k2][d];
        out[(size_t)(t2 * 1568 + b) * 1024 + h * 64 + d] = f2bf(o);
    }
}

// ---------------------------------------------------------------------------
// Spatial attention, MFMA version.  S'=197 (13 q-tiles of 16, 13 k-tiles),
// one block(256)=4 waves per (u=t*8+n, h).  K [208x72pad] and V^T [64x232pad]
// staged in LDS bf16; scores in C-layout regs; P round-trips LDS (C->A).
// ---------------------------------------------------------------------------
#define KLS 72
#define PVS 232
__global__ __launch_bounds__(256) void attn_s(const u16* __restrict__ qkv,
                                              const float* __restrict__ rpb,
                                              u16* __restrict__ out) {
    __shared__ u16 Kl[208 * KLS];        // [key][feat], rows 197..207 zero
    __shared__ u16 Vt[64 * PVS];         // [feat][key], cols 197..231 zero
    __shared__ u16 Pl[4][16 * PVS];      // per-wave P tile [qlocal][key]
    __shared__ float rpb_l[736];
    int blk = blockIdx.x;
    int u = blk & 63, h = blk >> 6;
    int tid = threadIdx.x;
    int w = tid >> 6, lane = tid & 63;
    int lm = lane & 15, quad = lane >> 4;

    // ---- stage K, V^T ----
    for (int idx = tid; idx < 197 * 8; idx += 256) {
        int s = idx >> 3, c8 = idx & 7;
        const u16* gp = qkv + (size_t)(s * 64 + u) * 3072 + h * 64 + c8 * 8;
        uint4 kv = *(const uint4*)(gp + 1024);
        uint4 vv = *(const uint4*)(gp + 2048);
        *(uint4*)&Kl[s * KLS + c8 * 8] = kv;
        const u16* vp = (const u16*)&vv;
#pragma unroll
        for (int j = 0; j < 8; j++) Vt[(c8 * 8 + j) * PVS + s] = vp[j];
    }
    for (int i = tid; i < 11 * KLS; i += 256) Kl[197 * KLS + i] = 0;
    for (int i = tid; i < 64 * 35; i += 256) {
        int dd = i / 35, c = 197 + (i - dd * 35);
        Vt[dd * PVS + c] = 0;
    }
    { // zero P pad cols 208..223 (never rewritten)
        for (int i = lane; i < 256; i += 64) {
            int r = i >> 4, c = 208 + (i & 15);
            Pl[w][r * PVS + c] = 0;
        }
    }
    for (int i = tid; i < 729; i += 256) rpb_l[i] = rpb[i * 16 + h];
    __syncthreads();

    for (int it = 0; it < 4; it++) {
        int qt = it * 4 + w;
        bool act = qt < 13;
        f32x4 sc[13];
        float rs[4];
        if (act) {
            // Q A-frags straight from global: A[m=lm][k=quad*8+j]
            int qrow = qt * 16 + lm;
            int srq = qrow > 196 ? 196 : qrow;
            const u16* qp = qkv + (size_t)(srq * 64 + u) * 3072 + h * 64 + quad * 8;
            bf16x8 aq0 = *(const bf16x8*)qp;
            bf16x8 aq1 = *(const bf16x8*)(qp + 32);
            for (int kt = 0; kt < 13; kt++) {
                bf16x8 bk0 = *(const bf16x8*)&Kl[(kt * 16 + lm) * KLS + quad * 8];
                bf16x8 bk1 = *(const bf16x8*)&Kl[(kt * 16 + lm) * KLS + 32 + quad * 8];
                f32x4 s = __builtin_amdgcn_mfma_f32_16x16x32_bf16(aq0, bk0, (f32x4){0.f, 0.f, 0.f, 0.f}, 0, 0, 0);
                sc[kt] = __builtin_amdgcn_mfma_f32_16x16x32_bf16(aq1, bk1, s, 0, 0, 0);
            }
            // bias + mask (C-layout: col=lm per tile, row=quad*4+r)
            int tk = lm;  // per-tile col base added in loop
#pragma unroll
            for (int r = 0; r < 4; r++) {
                int qr = qt * 16 + quad * 4 + r;
                int qcl = qr > 196 ? 196 : qr;
                int lq = qcl - 1;
                int qi = lq / 14, qj = lq - qi * 14;
                for (int kt = 0; kt < 13; kt++) {
                    int tkk = kt * 16 + tk;
                    float v;
                    if (tkk >= 197) v = -1e30f;
                    else {
                        v = sc[kt][r] * 0.125f;
                        if (qr >= 1 && tkk >= 1) {
                            int lk = tkk - 1;
                            int ki = lk / 14, kj = lk - ki * 14;
                            v += rpb_l[(qi - ki + 13) * 27 + (qj - kj + 13)];
                        }
                    }
                    sc[kt][r] = v;
                }
                float mx = -3e38f;
                for (int kt = 0; kt < 13; kt++) mx = fmaxf(mx, sc[kt][r]);
                mx = fmaxf(mx, __shfl_xor(mx, 1));
                mx = fmaxf(mx, __shfl_xor(mx, 2));
                mx = fmaxf(mx, __shfl_xor(mx, 4));
                mx = fmaxf(mx, __shfl_xor(mx, 8));
                float sm = 0.f;
                for (int kt = 0; kt < 13; kt++) {
                    float p = __expf(sc[kt][r] - mx);
                    sc[kt][r] = p;
                    sm += p;
                }
                sm += __shfl_xor(sm, 1);
                sm += __shfl_xor(sm, 2);
                sm += __shfl_xor(sm, 4);
                sm += __shfl_xor(sm, 8);
                rs[r] = sm;
                // write P (bf16) into per-wave LDS tile
                for (int kt = 0; kt < 13; kt++)
                    Pl[w][(quad * 4 + r) * PVS + kt * 16 + tk] = f2bf(sc[kt][r]);
            }
        }
        __syncthreads();
        if (act) {
            // PV: A-frags from Pl (row=qlocal, k=key), B-frags from Vt (row=d, k=key)
            bf16x8 pa[7];
#pragma unroll
            for (int kc = 0; kc < 7; kc++)
                pa[kc] = *(const bf16x8*)&Pl[w][lm * PVS + kc * 32 + quad * 8];
#pragma unroll
            for (int ct = 0; ct < 4; ct++) {
                f32x4 o = (f32x4){0.f, 0.f, 0.f, 0.f};
#pragma unroll
                for (int kc = 0; kc < 7; kc++) {
                    bf16x8 vb = *(const bf16x8*)&Vt[(ct * 16 + lm) * PVS + kc * 32 + quad * 8];
                    o = __builtin_amdgcn_mfma_f32_16x16x32_bf16(pa[kc], vb, o, 0, 0, 0);
                }
#pragma unroll
                for (int r = 0; r < 4; r++) {
                    int qr = qt * 16 + quad * 4 + r;
                    if (qr < 197)
                        out[(size_t)(qr * 64 + u) * 1024 + h * 64 + ct * 16 + lm] =
                            f2bf(o[r] / rs[r]);
                }
            }
        }
        __syncthreads();
    }
}

// ---------------------------------------------------------------------------
// Residual adds
// ---------------------------------------------------------------------------
__global__ __launch_bounds__(256) void add_cls(const u16* __restrict__ R, float* __restrict__ resid) {
    int tid = blockIdx.x * 256 + threadIdx.x;   // 8192
    int c = tid & 1023, n = tid >> 10;
    float s = 0.f;
#pragma unroll
    for (int t = 0; t < 8; t++) s += bf2f(R[(size_t)(t * 8 + n) * 1024 + c]);
    resid[tid] += s * 0.125f;
}

__global__ __launch_bounds__(256) void add_spa(const u16* __restrict__ R, float* __restrict__ resid) {
    int tid = blockIdx.x * 256 + threadIdx.x;   // 1568*8192
    int c = tid & 1023;
    int n = (tid >> 10) & 7;
    int r = tid >> 13;
    int t = r & 7, l = r >> 3;
    int srow = (l + 1) * 64 + t * 8 + n;
    resid[tid + 8192] += bf2f(R[(size_t)srow * 1024 + c]);
}

__global__ __launch_bounds__(256) void add_flat(const u16* __restrict__ R, float* __restrict__ resid) {
    int tid = blockIdx.x * 256 + threadIdx.x;   // 12552*1024
    resid[tid] += bf2f(R[tid]);
}

// ---------------------------------------------------------------------------
extern "C" void kernel_launch(void* const* d_in, const int* in_sizes, int n_in,
                              void* d_out, int out_size, void* d_ws, size_t ws_size,
                              hipStream_t stream) {
    const float* x      = (const float*)d_in[0];
    const float* pos_w  = (const float*)d_in[1];
    const float* pos_b  = (const float*)d_in[2];
    const float* ln_t_g = (const float*)d_in[3];
    const float* ln_t_b = (const float*)d_in[4];
    const float* rpb_t  = (const float*)d_in[5];
    const float* wqkv_t = (const float*)d_in[6];
    const float* bqkv_t = (const float*)d_in[7];
    const float* wo_t   = (const float*)d_in[8];
    const float* bo_t   = (const float*)d_in[9];
    const float* ln1_g  = (const float*)d_in[10];
    const float* ln1_b  = (const float*)d_in[11];
    const float* rpb_s  = (const float*)d_in[12];
    const float* wqkv_s = (const float*)d_in[13];
    const float* bqkv_s = (const float*)d_in[14];
    const float* wo_s   = (const float*)d_in[15];
    const float* bo_s   = (const float*)d_in[16];
    const float* ln2_g  = (const float*)d_in[17];
    const float* ln2_b  = (const float*)d_in[18];
    const float* fc_w   = (const float*)d_in[19];
    const float* fc_b   = (const float*)d_in[20];
    const float* proj_w = (const float*)d_in[21];
    const float* proj_b = (const float*)d_in[22];
    float* resid = (float*)d_out;

    // workspace arena (bf16 elements)
    u16* Wq_t  = (u16*)d_ws;
    u16* Wo_t  = Wq_t + 3145728;
    u16* Wq_s  = Wo_t + 1048576;
    u16* Wo_s  = Wq_s + 3145728;
    u16* Wfc   = Wo_s + 1048576;
    u16* Wpj   = Wfc  + 4194304;
    u16* Albuf = Wpj  + 4194304;          // 12608*1024
    u16* QKV   = Albuf + 12910592;        // 12608*3072
    u16* Obuf  = QKV   + 38731776;        // 12608*1024
    u16* Rbuf  = Obuf  + 12910592;        // 12608*1024
    u16* Hbuf  = QKV;                     // alias: 12552*4096 fits in QKV+Obuf

    // weight conversion
    cvt_bf16<<<12288, 256, 0, stream>>>(wqkv_t, Wq_t, 3145728);
    cvt_bf16<<<4096,  256, 0, stream>>>(wo_t,   Wo_t, 1048576);
    cvt_bf16<<<12288, 256, 0, stream>>>(wqkv_s, Wq_s, 3145728);
    cvt_bf16<<<4096,  256, 0, stream>>>(wo_s,   Wo_s, 1048576);
    cvt_bf16<<<16384, 256, 0, stream>>>(fc_w,   Wfc,  4194304);
    cvt_bf16<<<16384, 256, 0, stream>>>(proj_w, Wpj,  4194304);

    // positional embedding -> resid (= xpe)
    posembed<<<50208, 256, 0, stream>>>(x, pos_w, pos_b, resid);

    // temporal attention (result NOT added to resid; feeds spatial LN only)
    ln_kernel<<<12544, 256, 0, stream>>>(resid, nullptr, ln_t_g, ln_t_b, Albuf, 0);
    gemm_bf16<<<dim3(24, 98), 256, 0, stream>>>(Albuf, Wq_t, bqkv_t, QKV, 12544, 3072, 1024, 0);
    attn_t<<<25088, 64, 0, stream>>>(QKV, rpb_t, Obuf);
    gemm_bf16<<<dim3(8, 98), 256, 0, stream>>>(Obuf, Wo_t, bo_t, Rbuf, 12544, 1024, 1024, 0);

    // spatial attention (LN1 fuses xt_full = xpe + rt gather)
    ln_kernel<<<12608, 256, 0, stream>>>(resid, Rbuf, ln1_g, ln1_b, Albuf, 1);
    gemm_bf16<<<dim3(24, 99), 256, 0, stream>>>(Albuf, Wq_s, bqkv_s, QKV, 12608, 3072, 1024, 0);
    attn_s<<<1024, 256, 0, stream>>>(QKV, rpb_s, Obuf);
    gemm_bf16<<<dim3(8, 99), 256, 0, stream>>>(Obuf, Wo_s, bo_s, Rbuf, 12608, 1024, 1024, 0);
    add_cls<<<32, 256, 0, stream>>>(Rbuf, resid);
    add_spa<<<50176, 256, 0, stream>>>(Rbuf, resid);

    // MLP with QuickGELU
    ln_kernel<<<12552, 256, 0, stream>>>(resid, nullptr, ln2_g, ln2_b, Albuf, 2);
    gemm_bf16<<<dim3(32, 99), 256, 0, stream>>>(Albuf, Wfc, fc_b, Hbuf, 12552, 4096, 1024, 1);
    gemm_bf16<<<dim3(8, 99), 256, 0, stream>>>(Hbuf, Wpj, proj_b, Rbuf, 12552, 1024, 4096, 0);
    add_flat<<<50208, 256, 0, stream>>>(Rbuf, resid);
}

// Round 3
// 1301.557 us; speedup vs baseline: 1.8275x; 1.2777x over previous
//
#include <hip/hip_runtime.h>
#include <stdint.h>

typedef unsigned short u16;
typedef __attribute__((ext_vector_type(8))) __bf16 bf16x8;
typedef __attribute__((ext_vector_type(4))) float f32x4;

__device__ __forceinline__ float bf2f(u16 u) {
    return __uint_as_float(((unsigned int)u) << 16);
}
__device__ __forceinline__ u16 f2bf(float f) {
    unsigned int u = __float_as_uint(f);
    u += 0x7fffu + ((u >> 16) & 1u);   // round-to-nearest-even
    return (u16)(u >> 16);
}

// async global->LDS, 16B per lane.  LDS dest = wave-uniform base + lane*16.
__device__ __forceinline__ void gl16(const u16* g, u16* l) {
    __builtin_amdgcn_global_load_lds(
        (const __attribute__((address_space(1))) unsigned int*)(uintptr_t)g,
        (__attribute__((address_space(3))) unsigned int*)(uintptr_t)l,
        16, 0, 0);
}

// ---------------------------------------------------------------------------
// f32 -> bf16 convert (weights), 4 elems/thread
// ---------------------------------------------------------------------------
__global__ __launch_bounds__(256) void cvt_bf16(const float4* __restrict__ in,
                                                ushort4* __restrict__ out, int n4) {
    int tid = blockIdx.x * 256 + threadIdx.x;
    if (tid < n4) {
        float4 v = in[tid];
        ushort4 o;
        o.x = f2bf(v.x); o.y = f2bf(v.y); o.z = f2bf(v.z); o.w = f2bf(v.w);
        out[tid] = o;
    }
}

// pos_w [1024][27] -> wt [27][1024] (float)
__global__ __launch_bounds__(256) void cvt_wt(const float* __restrict__ pw,
                                              float* __restrict__ wt) {
    int tid = blockIdx.x * 256 + threadIdx.x;   // 27648
    if (tid < 27648) {
        int tap = tid >> 10, c = tid & 1023;
        wt[tid] = pw[c * 27 + tap];
    }
}

// ---------------------------------------------------------------------------
// Depthwise 3x3x3 conv positional embedding, float4 vectorized.
// x4: [1569, 8, 256] float4; token r = (i*14+j)*8 + t; out = resid (xpe).
// rf is block-uniform (2048 float4 per row = 8 blocks/row) -> no divergence.
// ---------------------------------------------------------------------------
__global__ __launch_bounds__(256) void posembed(const float4* __restrict__ x4,
                                                const float4* __restrict__ wt4,
                                                const float4* __restrict__ pb4,
                                                float4* __restrict__ out4) {
    int tid = blockIdx.x * 256 + threadIdx.x;   // 1569*2048 total
    float4 xv = x4[tid];
    int rf = tid >> 11;
    if (rf == 0) { out4[tid] = xv; return; }
    int c4 = tid & 255;
    int n = (tid >> 8) & 7;
    int r = rf - 1;
    int t = r & 7, l = r >> 3;
    int i = l / 14, j = l - i * 14;
    float4 pbv = pb4[c4];
    float a0 = xv.x + pbv.x, a1 = xv.y + pbv.y, a2 = xv.z + pbv.z, a3 = xv.w + pbv.w;
#pragma unroll
    for (int dt = 0; dt < 3; dt++) {
        int tt = t + dt - 1;
        if (tt < 0 || tt > 7) continue;
#pragma unroll
        for (int di = 0; di < 3; di++) {
            int ii = i + di - 1;
            if (ii < 0 || ii > 13) continue;
#pragma unroll
            for (int dj = 0; dj < 3; dj++) {
                int jj = j + dj - 1;
                if (jj < 0 || jj > 13) continue;
                float4 w4 = wt4[(dt * 9 + di * 3 + dj) * 256 + c4];
                float4 v = x4[(size_t)(1 + ((ii * 14 + jj) << 3) + tt) * 2048 + (n << 8) + c4];
                a0 += w4.x * v.x; a1 += w4.y * v.y; a2 += w4.z * v.z; a3 += w4.w * v.w;
            }
        }
    }
    out4[tid] = (float4){a0, a1, a2, a3};
}

// ---------------------------------------------------------------------------
// LayerNorm with branch-specific row gather, f32 in -> bf16 out.
// ---------------------------------------------------------------------------
__global__ __launch_bounds__(256) void ln_kernel(const float* __restrict__ resid,
                                                 const u16* __restrict__ Radd,
                                                 const float* __restrict__ g,
                                                 const float* __restrict__ bb,
                                                 u16* __restrict__ out, int mode) {
    int ro = blockIdx.x;
    int tid = threadIdx.x;
    int src, n;
    long long rarow = -1;
    if (mode == 0) {
        int t = ro / 1568, b2 = ro - t * 1568;
        n = b2 / 196;
        int l = b2 - n * 196;
        src = 1 + l * 8 + t;
    } else if (mode == 1) {
        int s = ro >> 6, u = ro & 63;
        int t = u >> 3;
        n = u & 7;
        if (s == 0) src = 0;
        else { src = 1 + (s - 1) * 8 + t; rarow = (long long)(t * 1568 + n * 196 + (s - 1)); }
    } else {
        src = ro >> 3;
        n = ro & 7;
    }
    const float* xp = resid + ((size_t)src * 8 + n) * 1024 + tid * 4;
    float4 xv = *(const float4*)xp;
    float x0 = xv.x, x1 = xv.y, x2 = xv.z, x3 = xv.w;
    if (rarow >= 0) {
        const u16* rp = Radd + rarow * 1024 + tid * 4;
        x0 += bf2f(rp[0]); x1 += bf2f(rp[1]); x2 += bf2f(rp[2]); x3 += bf2f(rp[3]);
    }
    float s1 = x0 + x1 + x2 + x3;
    float s2 = x0 * x0 + x1 * x1 + x2 * x2 + x3 * x3;
#pragma unroll
    for (int off = 32; off > 0; off >>= 1) {
        s1 += __shfl_down(s1, off);
        s2 += __shfl_down(s2, off);
    }
    __shared__ float red[8];
    int lane = tid & 63, w = tid >> 6;
    if (lane == 0) { red[w] = s1; red[4 + w] = s2; }
    __syncthreads();
    float S1 = red[0] + red[1] + red[2] + red[3];
    float S2 = red[4] + red[5] + red[6] + red[7];
    float mean = S1 * (1.f / 1024.f);
    float var = S2 * (1.f / 1024.f) - mean * mean;
    float rstd = rsqrtf(var + 1e-5f);
    int c = tid * 4;
    u16* op = out + (size_t)ro * 1024 + c;
    op[0] = f2bf((x0 - mean) * rstd * g[c + 0] + bb[c + 0]);
    op[1] = f2bf((x1 - mean) * rstd * g[c + 1] + bb[c + 1]);
    op[2] = f2bf((x2 - mean) * rstd * g[c + 2] + bb[c + 2]);
    op[3] = f2bf((x3 - mean) * rstd * g[c + 3] + bb[c + 3]);
}

// ---------------------------------------------------------------------------
// bf16 MFMA GEMM:  C[M,N] = epi(A[M,K] @ W[N,K]^T + bias[N]),  bf16 out.
// 128x128 tile, BK=32, global_load_lds width-16 staging (m97 pattern).
// ---------------------------------------------------------------------------
__global__ __launch_bounds__(256) void gemm_bf16(const u16* __restrict__ A,
                                                 const u16* __restrict__ W,
                                                 const float* __restrict__ bias,
                                                 u16* __restrict__ Co,
                                                 int M, int N, int K, int gelu) {
    __shared__ u16 As[128 * 32];
    __shared__ u16 Bs[128 * 32];
    int tid = threadIdx.x;
    int n0 = blockIdx.x * 128, m0 = blockIdx.y * 128;
    int lane = tid & 63, wid = tid >> 6;
    int wm = (wid >> 1) * 64, wn = (wid & 1) * 64;
    int lm = lane & 15, q = lane >> 4;

    f32x4 acc[4][4];
#pragma unroll
    for (int i = 0; i < 4; i++)
#pragma unroll
        for (int j = 0; j < 4; j++) acc[i][j] = (f32x4){0.f, 0.f, 0.f, 0.f};

    // staging map: wave w chunk c (c=0,1): lane l -> row w*32+c*16+(l>>2), col bf16 (l&3)*8
    int r0 = wid * 32 + (lane >> 2);
    int colb = (lane & 3) * 8;
    int mA0 = m0 + r0;          if (mA0 > M - 1) mA0 = M - 1;
    int mA1 = m0 + r0 + 16;     if (mA1 > M - 1) mA1 = M - 1;
    const u16* gA0 = A + (size_t)mA0 * K + colb;
    const u16* gA1 = A + (size_t)mA1 * K + colb;
    const u16* gB0 = W + (size_t)(n0 + r0) * K + colb;
    const u16* gB1 = W + (size_t)(n0 + r0 + 16) * K + colb;
    u16* lA0 = &As[wid * 1024];
    u16* lA1 = &As[wid * 1024 + 512];
    u16* lB0 = &Bs[wid * 1024];
    u16* lB1 = &Bs[wid * 1024 + 512];

    for (int k0 = 0; k0 < K; k0 += 32) {
        gl16(gA0, lA0); gl16(gA1, lA1);
        gl16(gB0, lB0); gl16(gB1, lB1);
        gA0 += 32; gA1 += 32; gB0 += 32; gB1 += 32;
        __syncthreads();              // drain vmcnt -> staged data visible
        bf16x8 af[4], bfr[4];
#pragma unroll
        for (int i = 0; i < 4; i++) af[i] = *(const bf16x8*)&As[(wm + i * 16 + lm) * 32 + q * 8];
#pragma unroll
        for (int j = 0; j < 4; j++) bfr[j] = *(const bf16x8*)&Bs[(wn + j * 16 + lm) * 32 + q * 8];
#pragma unroll
        for (int i = 0; i < 4; i++)
#pragma unroll
            for (int j = 0; j < 4; j++)
                acc[i][j] = __builtin_amdgcn_mfma_f32_16x16x32_bf16(af[i], bfr[j], acc[i][j], 0, 0, 0);
        __syncthreads();              // reads done before next overwrite
    }

#pragma unroll
    for (int i = 0; i < 4; i++) {
        int row_b = m0 + wm + i * 16 + q * 4;
#pragma unroll
        for (int j = 0; j < 4; j++) {
            int col = n0 + wn + j * 16 + lm;
            float bv = bias[col];
#pragma unroll
            for (int r = 0; r < 4; r++) {
                int row = row_b + r;
                if (row < M) {
                    float v = acc[i][j][r] + bv;
                    if (gelu) v = v / (1.f + __expf(-1.702f * v));  // QuickGELU
                    Co[(size_t)row * N + col] = f2bf(v);
                }
            }
        }
    }
}

// ---------------------------------------------------------------------------
// Temporal attention: S=8, one wave per (b, h).
// ---------------------------------------------------------------------------
__global__ __launch_bounds__(64) void attn_t(const u16* __restrict__ qkv,
                                             const float* __restrict__ rpb,
                                             u16* __restrict__ out) {
    int blk = blockIdx.x;
    int b = blk % 1568, h = blk / 1568;
    int d = threadIdx.x;
    __shared__ float qs[8][65], ks[8][65], vs[8][65];
    __shared__ float ps[8][9];
#pragma unroll
    for (int t = 0; t < 8; t++) {
        size_t row = (size_t)(t * 1568 + b) * 3072 + h * 64 + d;
        qs[t][d] = bf2f(qkv[row]) * 0.125f;
        ks[t][d] = bf2f(qkv[row + 1024]);
        vs[t][d] = bf2f(qkv[row + 2048]);
    }
    __syncthreads();
    int tq = d >> 3, tk = d & 7;
    float s = rpb[(tq - tk + 7) * 16 + h];
#pragma unroll
    for (int dd = 0; dd < 64; dd++) s += qs[tq][dd] * ks[tk][dd];
    float mx = s;
    mx = fmaxf(mx, __shfl_xor(mx, 1));
    mx = fmaxf(mx, __shfl_xor(mx, 2));
    mx = fmaxf(mx, __shfl_xor(mx, 4));
    float p = __expf(s - mx);
    float su = p;
    su += __shfl_xor(su, 1);
    su += __shfl_xor(su, 2);
    su += __shfl_xor(su, 4);
    ps[tq][tk] = p / su;
    __syncthreads();
#pragma unroll
    for (int t2 = 0; t2 < 8; t2++) {
        float o = 0.f;
#pragma unroll
        for (int k2 = 0; k2 < 8; k2++) o += ps[t2][k2] * vs[k2][d];
        out[(size_t)(t2 * 1568 + b) * 1024 + h * 64 + d] = f2bf(o);
    }
}

// ---------------------------------------------------------------------------
// Spatial attention, MFMA version.  S'=197 (13 q-tiles of 16, 13 k-tiles),
// one block(256)=4 waves per (u=t*8+n, h).
// ---------------------------------------------------------------------------
#define KLS 72
#define PVS 232
__global__ __launch_bounds__(256) void attn_s(const u16* __restrict__ qkv,
                                              const float* __restrict__ rpb,
                                              u16* __restrict__ out) {
    __shared__ u16 Kl[208 * KLS];        // [key][feat], rows 197..207 zero
    __shared__ u16 Vt[64 * PVS];         // [feat][key], cols 197..231 zero
    __shared__ u16 Pl[4][16 * PVS];      // per-wave P tile [qlocal][key]
    __shared__ float rpb_l[736];
    int blk = blockIdx.x;
    int u = blk & 63, h = blk >> 6;
    int tid = threadIdx.x;
    int w = tid >> 6, lane = tid & 63;
    int lm = lane & 15, quad = lane >> 4;

    // ---- stage K, V^T ----
    for (int idx = tid; idx < 197 * 8; idx += 256) {
        int s = idx >> 3, c8 = idx & 7;
        const u16* gp = qkv + (size_t)(s * 64 + u) * 3072 + h * 64 + c8 * 8;
        uint4 kv = *(const uint4*)(gp + 1024);
        uint4 vv = *(const uint4*)(gp + 2048);
        *(uint4*)&Kl[s * KLS + c8 * 8] = kv;
        const u16* vp = (const u16*)&vv;
#pragma unroll
        for (int j = 0; j < 8; j++) Vt[(c8 * 8 + j) * PVS + s] = vp[j];
    }
    for (int i = tid; i < 11 * KLS; i += 256) Kl[197 * KLS + i] = 0;
    for (int i = tid; i < 64 * 35; i += 256) {
        int dd = i / 35, c = 197 + (i - dd * 35);
        Vt[dd * PVS + c] = 0;
    }
    { // zero P pad cols 208..223 (never rewritten)
        for (int i = lane; i < 256; i += 64) {
            int r = i >> 4, c = 208 + (i & 15);
            Pl[w][r * PVS + c] = 0;
        }
    }
    for (int i = tid; i < 729; i += 256) rpb_l[i] = rpb[i * 16 + h];
    __syncthreads();

    for (int it = 0; it < 4; it++) {
        int qt = it * 4 + w;
        bool act = qt < 13;
        f32x4 sc[13];
        float rs[4];
        if (act) {
            // Q A-frags straight from global: A[m=lm][k=quad*8+j]
            int qrow = qt * 16 + lm;
            int srq = qrow > 196 ? 196 : qrow;
            const u16* qp = qkv + (size_t)(srq * 64 + u) * 3072 + h * 64 + quad * 8;
            bf16x8 aq0 = *(const bf16x8*)qp;
            bf16x8 aq1 = *(const bf16x8*)(qp + 32);
            for (int kt = 0; kt < 13; kt++) {
                bf16x8 bk0 = *(const bf16x8*)&Kl[(kt * 16 + lm) * KLS + quad * 8];
                bf16x8 bk1 = *(const bf16x8*)&Kl[(kt * 16 + lm) * KLS + 32 + quad * 8];
                f32x4 s = __builtin_amdgcn_mfma_f32_16x16x32_bf16(aq0, bk0, (f32x4){0.f, 0.f, 0.f, 0.f}, 0, 0, 0);
                sc[kt] = __builtin_amdgcn_mfma_f32_16x16x32_bf16(aq1, bk1, s, 0, 0, 0);
            }
            int tk = lm;
#pragma unroll
            for (int r = 0; r < 4; r++) {
                int qr = qt * 16 + quad * 4 + r;
                int qcl = qr > 196 ? 196 : qr;
                int lq = qcl - 1;
                int qi = lq / 14, qj = lq - qi * 14;
                for (int kt = 0; kt < 13; kt++) {
                    int tkk = kt * 16 + tk;
                    float v;
                    if (tkk >= 197) v = -1e30f;
                    else {
                        v = sc[kt][r] * 0.125f;
                        if (qr >= 1 && tkk >= 1) {
                            int lk = tkk - 1;
                            int ki = lk / 14, kj = lk - ki * 14;
                            v += rpb_l[(qi - ki + 13) * 27 + (qj - kj + 13)];
                        }
                    }
                    sc[kt][r] = v;
                }
                float mx = -3e38f;
                for (int kt = 0; kt < 13; kt++) mx = fmaxf(mx, sc[kt][r]);
                mx = fmaxf(mx, __shfl_xor(mx, 1));
                mx = fmaxf(mx, __shfl_xor(mx, 2));
                mx = fmaxf(mx, __shfl_xor(mx, 4));
                mx = fmaxf(mx, __shfl_xor(mx, 8));
                float sm = 0.f;
                for (int kt = 0; kt < 13; kt++) {
                    float p = __expf(sc[kt][r] - mx);
                    sc[kt][r] = p;
                    sm += p;
                }
                sm += __shfl_xor(sm, 1);
                sm += __shfl_xor(sm, 2);
                sm += __shfl_xor(sm, 4);
                sm += __shfl_xor(sm, 8);
                rs[r] = sm;
                for (int kt = 0; kt < 13; kt++)
                    Pl[w][(quad * 4 + r) * PVS + kt * 16 + tk] = f2bf(sc[kt][r]);
            }
        }
        __syncthreads();
        if (act) {
            bf16x8 pa[7];
#pragma unroll
            for (int kc = 0; kc < 7; kc++)
                pa[kc] = *(const bf16x8*)&Pl[w][lm * PVS + kc * 32 + quad * 8];
#pragma unroll
            for (int ct = 0; ct < 4; ct++) {
                f32x4 o = (f32x4){0.f, 0.f, 0.f, 0.f};
#pragma unroll
                for (int kc = 0; kc < 7; kc++) {
                    bf16x8 vb = *(const bf16x8*)&Vt[(ct * 16 + lm) * PVS + kc * 32 + quad * 8];
                    o = __builtin_amdgcn_mfma_f32_16x16x32_bf16(pa[kc], vb, o, 0, 0, 0);
                }
#pragma unroll
                for (int r = 0; r < 4; r++) {
                    int qr = qt * 16 + quad * 4 + r;
                    if (qr < 197)
                        out[(size_t)(qr * 64 + u) * 1024 + h * 64 + ct * 16 + lm] =
                            f2bf(o[r] / rs[r]);
                }
            }
        }
        __syncthreads();
    }
}

// ---------------------------------------------------------------------------
// Residual adds (float4 vectorized)
// ---------------------------------------------------------------------------
__global__ __launch_bounds__(256) void add_cls(const u16* __restrict__ R, float4* __restrict__ resid4) {
    int tid = blockIdx.x * 256 + threadIdx.x;   // 2048
    int c4 = tid & 255, n = tid >> 8;
    float s0 = 0.f, s1 = 0.f, s2 = 0.f, s3 = 0.f;
#pragma unroll
    for (int t = 0; t < 8; t++) {
        ushort4 rv = *(const ushort4*)&R[(size_t)(t * 8 + n) * 1024 + c4 * 4];
        s0 += bf2f(rv.x); s1 += bf2f(rv.y); s2 += bf2f(rv.z); s3 += bf2f(rv.w);
    }
    float4 v = resid4[tid];
    v.x += s0 * 0.125f; v.y += s1 * 0.125f; v.z += s2 * 0.125f; v.w += s3 * 0.125f;
    resid4[tid] = v;
}

__global__ __launch_bounds__(256) void add_spa(const u16* __restrict__ R, float4* __restrict__ resid4) {
    int tid = blockIdx.x * 256 + threadIdx.x;   // 1568*2048
    int c4 = tid & 255;
    int n = (tid >> 8) & 7;
    int r = tid >> 11;
    int t = r & 7, l = r >> 3;
    int srow = (l + 1) * 64 + t * 8 + n;
    ushort4 rv = *(const ushort4*)&R[(size_t)srow * 1024 + c4 * 4];
    float4 v = resid4[tid + 2048];
    v.x += bf2f(rv.x); v.y += bf2f(rv.y); v.z += bf2f(rv.z); v.w += bf2f(rv.w);
    resid4[tid + 2048] = v;
}

__global__ __launch_bounds__(256) void add_flat(const ushort4* __restrict__ R4, float4* __restrict__ resid4) {
    int tid = blockIdx.x * 256 + threadIdx.x;   // 12552*256
    ushort4 rv = R4[tid];
    float4 v = resid4[tid];
    v.x += bf2f(rv.x); v.y += bf2f(rv.y); v.z += bf2f(rv.z); v.w += bf2f(rv.w);
    resid4[tid] = v;
}

// ---------------------------------------------------------------------------
extern "C" void kernel_launch(void* const* d_in, const int* in_sizes, int n_in,
                              void* d_out, int out_size, void* d_ws, size_t ws_size,
                              hipStream_t stream) {
    const float* x      = (const float*)d_in[0];
    const float* pos_w  = (const float*)d_in[1];
    const float* pos_b  = (const float*)d_in[2];
    const float* ln_t_g = (const float*)d_in[3];
    const float* ln_t_b = (const float*)d_in[4];
    const float* rpb_t  = (const float*)d_in[5];
    const float* wqkv_t = (const float*)d_in[6];
    const float* bqkv_t = (const float*)d_in[7];
    const float* wo_t   = (const float*)d_in[8];
    const float* bo_t   = (const float*)d_in[9];
    const float* ln1_g  = (const float*)d_in[10];
    const float* ln1_b  = (const float*)d_in[11];
    const float* rpb_s  = (const float*)d_in[12];
    const float* wqkv_s = (const float*)d_in[13];
    const float* bqkv_s = (const float*)d_in[14];
    const float* wo_s   = (const float*)d_in[15];
    const float* bo_s   = (const float*)d_in[16];
    const float* ln2_g  = (const float*)d_in[17];
    const float* ln2_b  = (const float*)d_in[18];
    const float* fc_w   = (const float*)d_in[19];
    const float* fc_b   = (const float*)d_in[20];
    const float* proj_w = (const float*)d_in[21];
    const float* proj_b = (const float*)d_in[22];
    float* resid = (float*)d_out;

    // workspace arena (bf16 elements)
    u16* Wq_t  = (u16*)d_ws;
    u16* Wo_t  = Wq_t + 3145728;
    u16* Wq_s  = Wo_t + 1048576;
    u16* Wo_s  = Wq_s + 3145728;
    u16* Wfc   = Wo_s + 1048576;
    u16* Wpj   = Wfc  + 4194304;
    u16* Albuf = Wpj  + 4194304;          // 12608*1024
    u16* QKV   = Albuf + 12910592;        // 12608*3072
    u16* Obuf  = QKV   + 38731776;        // 12608*1024
    u16* Rbuf  = Obuf  + 12910592;        // 12608*1024
    u16* Hbuf  = QKV;                     // alias: 12552*4096 fits in QKV+Obuf
    float* wt  = (float*)QKV;             // alias: 27*1024 f32, used only by posembed

    // weight conversion
    cvt_bf16<<<3072, 256, 0, stream>>>((const float4*)wqkv_t, (ushort4*)Wq_t, 786432);
    cvt_bf16<<<1024, 256, 0, stream>>>((const float4*)wo_t,   (ushort4*)Wo_t, 262144);
    cvt_bf16<<<3072, 256, 0, stream>>>((const float4*)wqkv_s, (ushort4*)Wq_s, 786432);
    cvt_bf16<<<1024, 256, 0, stream>>>((const float4*)wo_s,   (ushort4*)Wo_s, 262144);
    cvt_bf16<<<4096, 256, 0, stream>>>((const float4*)fc_w,   (ushort4*)Wfc,  1048576);
    cvt_bf16<<<4096, 256, 0, stream>>>((const float4*)proj_w, (ushort4*)Wpj,  1048576);
    cvt_wt<<<108, 256, 0, stream>>>(pos_w, wt);

    // positional embedding -> resid (= xpe)
    posembed<<<12552, 256, 0, stream>>>((const float4*)x, (const float4*)wt,
                                        (const float4*)pos_b, (float4*)resid);

    // temporal attention (result NOT added to resid; feeds spatial LN only)
    ln_kernel<<<12544, 256, 0, stream>>>(resid, nullptr, ln_t_g, ln_t_b, Albuf, 0);
    gemm_bf16<<<dim3(24, 98), 256, 0, stream>>>(Albuf, Wq_t, bqkv_t, QKV, 12544, 3072, 1024, 0);
    attn_t<<<25088, 64, 0, stream>>>(QKV, rpb_t, Obuf);
    gemm_bf16<<<dim3(8, 98), 256, 0, stream>>>(Obuf, Wo_t, bo_t, Rbuf, 12544, 1024, 1024, 0);

    // spatial attention (LN1 fuses xt_full = xpe + rt gather)
    ln_kernel<<<12608, 256, 0, stream>>>(resid, Rbuf, ln1_g, ln1_b, Albuf, 1);
    gemm_bf16<<<dim3(24, 99), 256, 0, stream>>>(Albuf, Wq_s, bqkv_s, QKV, 12608, 3072, 1024, 0);
    attn_s<<<1024, 256, 0, stream>>>(QKV, rpb_s, Obuf);
    gemm_bf16<<<dim3(8, 99), 256, 0, stream>>>(Obuf, Wo_s, bo_s, Rbuf, 12608, 1024, 1024, 0);
    add_cls<<<8, 256, 0, stream>>>(Rbuf, (float4*)resid);
    add_spa<<<12544, 256, 0, stream>>>(Rbuf, (float4*)resid);

    // MLP with QuickGELU
    ln_kernel<<<12552, 256, 0, stream>>>(resid, nullptr, ln2_g, ln2_b, Albuf, 2);
    gemm_bf16<<<dim3(32, 99), 256, 0, stream>>>(Albuf, Wfc, fc_b, Hbuf, 12552, 4096, 1024, 1);
    gemm_bf16<<<dim3(8, 99), 256, 0, stream>>>(Hbuf, Wpj, proj_b, Rbuf, 12552, 1024, 4096, 0);
    add_flat<<<12552, 256, 0, stream>>>((const ushort4*)Rbuf, (float4*)resid);
}

// Round 4
// 1176.429 us; speedup vs baseline: 2.0219x; 1.1064x over previous
//
#include <hip/hip_runtime.h>
#include <stdint.h>

typedef unsigned short u16;
typedef __attribute__((ext_vector_type(8))) __bf16 bf16x8;
typedef __attribute__((ext_vector_type(4))) float f32x4;

__device__ __forceinline__ float bf2f(u16 u) {
    return __uint_as_float(((unsigned int)u) << 16);
}
__device__ __forceinline__ u16 f2bf(float f) {
    unsigned int u = __float_as_uint(f);
    u += 0x7fffu + ((u >> 16) & 1u);   // round-to-nearest-even
    return (u16)(u >> 16);
}

// async global->LDS, 16B per lane.  LDS dest = wave-uniform base + lane*16.
__device__ __forceinline__ void gl16(const u16* g, u16* l) {
    __builtin_amdgcn_global_load_lds(
        (const __attribute__((address_space(1))) unsigned int*)(uintptr_t)g,
        (__attribute__((address_space(3))) unsigned int*)(uintptr_t)l,
        16, 0, 0);
}

// ---------------------------------------------------------------------------
// f32 -> bf16 convert (weights), 4 elems/thread
// ---------------------------------------------------------------------------
__global__ __launch_bounds__(256) void cvt_bf16(const float4* __restrict__ in,
                                                ushort4* __restrict__ out, int n4) {
    int tid = blockIdx.x * 256 + threadIdx.x;
    if (tid < n4) {
        float4 v = in[tid];
        ushort4 o;
        o.x = f2bf(v.x); o.y = f2bf(v.y); o.z = f2bf(v.z); o.w = f2bf(v.w);
        out[tid] = o;
    }
}

// pos_w [1024][27] -> wt [27][1024] (float)
__global__ __launch_bounds__(256) void cvt_wt(const float* __restrict__ pw,
                                              float* __restrict__ wt) {
    int tid = blockIdx.x * 256 + threadIdx.x;   // 27648
    if (tid < 27648) {
        int tap = tid >> 10, c = tid & 1023;
        wt[tid] = pw[c * 27 + tap];
    }
}

// ---------------------------------------------------------------------------
// Depthwise 3x3x3 conv positional embedding, float4 vectorized.
// ---------------------------------------------------------------------------
__global__ __launch_bounds__(256) void posembed(const float4* __restrict__ x4,
                                                const float4* __restrict__ wt4,
                                                const float4* __restrict__ pb4,
                                                float4* __restrict__ out4) {
    int tid = blockIdx.x * 256 + threadIdx.x;   // 1569*2048 total
    float4 xv = x4[tid];
    int rf = tid >> 11;
    if (rf == 0) { out4[tid] = xv; return; }
    int c4 = tid & 255;
    int n = (tid >> 8) & 7;
    int r = rf - 1;
    int t = r & 7, l = r >> 3;
    int i = l / 14, j = l - i * 14;
    float4 pbv = pb4[c4];
    float a0 = xv.x + pbv.x, a1 = xv.y + pbv.y, a2 = xv.z + pbv.z, a3 = xv.w + pbv.w;
#pragma unroll
    for (int dt = 0; dt < 3; dt++) {
        int tt = t + dt - 1;
        if (tt < 0 || tt > 7) continue;
#pragma unroll
        for (int di = 0; di < 3; di++) {
            int ii = i + di - 1;
            if (ii < 0 || ii > 13) continue;
#pragma unroll
            for (int dj = 0; dj < 3; dj++) {
                int jj = j + dj - 1;
                if (jj < 0 || jj > 13) continue;
                float4 w4 = wt4[(dt * 9 + di * 3 + dj) * 256 + c4];
                float4 v = x4[(size_t)(1 + ((ii * 14 + jj) << 3) + tt) * 2048 + (n << 8) + c4];
                a0 += w4.x * v.x; a1 += w4.y * v.y; a2 += w4.z * v.z; a3 += w4.w * v.w;
            }
        }
    }
    out4[tid] = (float4){a0, a1, a2, a3};
}

// ---------------------------------------------------------------------------
// LayerNorm with branch-specific row gather, f32 in -> bf16 out.
// ---------------------------------------------------------------------------
__global__ __launch_bounds__(256) void ln_kernel(const float* __restrict__ resid,
                                                 const u16* __restrict__ Radd,
                                                 const float* __restrict__ g,
                                                 const float* __restrict__ bb,
                                                 u16* __restrict__ out, int mode) {
    int ro = blockIdx.x;
    int tid = threadIdx.x;
    int src, n;
    long long rarow = -1;
    if (mode == 0) {
        int t = ro / 1568, b2 = ro - t * 1568;
        n = b2 / 196;
        int l = b2 - n * 196;
        src = 1 + l * 8 + t;
    } else if (mode == 1) {
        int s = ro >> 6, u = ro & 63;
        int t = u >> 3;
        n = u & 7;
        if (s == 0) src = 0;
        else { src = 1 + (s - 1) * 8 + t; rarow = (long long)(t * 1568 + n * 196 + (s - 1)); }
    } else {
        src = ro >> 3;
        n = ro & 7;
    }
    const float* xp = resid + ((size_t)src * 8 + n) * 1024 + tid * 4;
    float4 xv = *(const float4*)xp;
    float x0 = xv.x, x1 = xv.y, x2 = xv.z, x3 = xv.w;
    if (rarow >= 0) {
        const u16* rp = Radd + rarow * 1024 + tid * 4;
        x0 += bf2f(rp[0]); x1 += bf2f(rp[1]); x2 += bf2f(rp[2]); x3 += bf2f(rp[3]);
    }
    float s1 = x0 + x1 + x2 + x3;
    float s2 = x0 * x0 + x1 * x1 + x2 * x2 + x3 * x3;
#pragma unroll
    for (int off = 32; off > 0; off >>= 1) {
        s1 += __shfl_down(s1, off);
        s2 += __shfl_down(s2, off);
    }
    __shared__ float red[8];
    int lane = tid & 63, w = tid >> 6;
    if (lane == 0) { red[w] = s1; red[4 + w] = s2; }
    __syncthreads();
    float S1 = red[0] + red[1] + red[2] + red[3];
    float S2 = red[4] + red[5] + red[6] + red[7];
    float mean = S1 * (1.f / 1024.f);
    float var = S2 * (1.f / 1024.f) - mean * mean;
    float rstd = rsqrtf(var + 1e-5f);
    int c = tid * 4;
    u16* op = out + (size_t)ro * 1024 + c;
    op[0] = f2bf((x0 - mean) * rstd * g[c + 0] + bb[c + 0]);
    op[1] = f2bf((x1 - mean) * rstd * g[c + 1] + bb[c + 1]);
    op[2] = f2bf((x2 - mean) * rstd * g[c + 2] + bb[c + 2]);
    op[3] = f2bf((x3 - mean) * rstd * g[c + 3] + bb[c + 3]);
}

// ---------------------------------------------------------------------------
// bf16 MFMA GEMM:  C[M,N] = epi(A[M,K] @ W[N,K]^T + bias[N]),  bf16 out.
// 128x128 tile, BK=32, double-buffered LDS, gl16 prefetch issued before
// compute (one barrier/iter), XCD-swizzled 1D grid (n-index fastest per XCD).
// ---------------------------------------------------------------------------
__global__ __launch_bounds__(256) void gemm_bf16(const u16* __restrict__ A,
                                                 const u16* __restrict__ W,
                                                 const float* __restrict__ bias,
                                                 u16* __restrict__ Co,
                                                 int M, int N, int K, int gelu,
                                                 int nx) {
    __shared__ u16 As[2][128 * 32];
    __shared__ u16 Bs[2][128 * 32];
    int tid = threadIdx.x;
    int T = gridDim.x;                       // divisible by 8
    int bid = blockIdx.x;
    int w_ = (bid & 7) * (T >> 3) + (bid >> 3);   // XCD g gets contiguous work range
    int n0 = (w_ % nx) * 128;
    int m0 = (w_ / nx) * 128;
    int lane = tid & 63, wid = tid >> 6;
    int wm = (wid >> 1) * 64, wn = (wid & 1) * 64;
    int lm = lane & 15, q = lane >> 4;

    f32x4 acc[4][4];
#pragma unroll
    for (int i = 0; i < 4; i++)
#pragma unroll
        for (int j = 0; j < 4; j++) acc[i][j] = (f32x4){0.f, 0.f, 0.f, 0.f};

    // staging map: wave w chunk c (c=0,1): lane l -> row w*32+c*16+(l>>2), col bf16 (l&3)*8
    int r0 = wid * 32 + (lane >> 2);
    int colb = (lane & 3) * 8;
    int mA0 = m0 + r0;          if (mA0 > M - 1) mA0 = M - 1;
    int mA1 = m0 + r0 + 16;     if (mA1 > M - 1) mA1 = M - 1;
    const u16* gA0 = A + (size_t)mA0 * K + colb;
    const u16* gA1 = A + (size_t)mA1 * K + colb;
    const u16* gB0 = W + (size_t)(n0 + r0) * K + colb;
    const u16* gB1 = W + (size_t)(n0 + r0 + 16) * K + colb;
    int wo = wid * 1024;

    auto loadt = [&](int b) {
        gl16(gA0, &As[b][wo]); gl16(gA1, &As[b][wo + 512]);
        gl16(gB0, &Bs[b][wo]); gl16(gB1, &Bs[b][wo + 512]);
        gA0 += 32; gA1 += 32; gB0 += 32; gB1 += 32;
    };
    auto comput = [&](int b) {
        bf16x8 af[4], bfr[4];
#pragma unroll
        for (int i = 0; i < 4; i++) af[i] = *(const bf16x8*)&As[b][(wm + i * 16 + lm) * 32 + q * 8];
#pragma unroll
        for (int j = 0; j < 4; j++) bfr[j] = *(const bf16x8*)&Bs[b][(wn + j * 16 + lm) * 32 + q * 8];
#pragma unroll
        for (int i = 0; i < 4; i++)
#pragma unroll
            for (int j = 0; j < 4; j++)
                acc[i][j] = __builtin_amdgcn_mfma_f32_16x16x32_bf16(af[i], bfr[j], acc[i][j], 0, 0, 0);
    };

    int Tt = K >> 5;                       // tiles; K is a multiple of 64
    loadt(0);
    __syncthreads();
    loadt(1); comput(0); __syncthreads();
    for (int t = 2; t + 1 < Tt; t += 2) {
        loadt(0); comput(1); __syncthreads();
        loadt(1); comput(0); __syncthreads();
    }
    comput(1);

#pragma unroll
    for (int i = 0; i < 4; i++) {
        int row_b = m0 + wm + i * 16 + q * 4;
#pragma unroll
        for (int j = 0; j < 4; j++) {
            int col = n0 + wn + j * 16 + lm;
            float bv = bias[col];
#pragma unroll
            for (int r = 0; r < 4; r++) {
                int row = row_b + r;
                if (row < M) {
                    float v = acc[i][j][r] + bv;
                    if (gelu) v = v / (1.f + __expf(-1.702f * v));  // QuickGELU
                    Co[(size_t)row * N + col] = f2bf(v);
                }
            }
        }
    }
}

// ---------------------------------------------------------------------------
// Temporal attention: S=8, one wave per (b, h).
// ---------------------------------------------------------------------------
__global__ __launch_bounds__(64) void attn_t(const u16* __restrict__ qkv,
                                             const float* __restrict__ rpb,
                                             u16* __restrict__ out) {
    int blk = blockIdx.x;
    int b = blk % 1568, h = blk / 1568;
    int d = threadIdx.x;
    __shared__ float qs[8][65], ks[8][65], vs[8][65];
    __shared__ float ps[8][9];
#pragma unroll
    for (int t = 0; t < 8; t++) {
        size_t row = (size_t)(t * 1568 + b) * 3072 + h * 64 + d;
        qs[t][d] = bf2f(qkv[row]) * 0.125f;
        ks[t][d] = bf2f(qkv[row + 1024]);
        vs[t][d] = bf2f(qkv[row + 2048]);
    }
    __syncthreads();
    int tq = d >> 3, tk = d & 7;
    float s = rpb[(tq - tk + 7) * 16 + h];
#pragma unroll
    for (int dd = 0; dd < 64; dd++) s += qs[tq][dd] * ks[tk][dd];
    float mx = s;
    mx = fmaxf(mx, __shfl_xor(mx, 1));
    mx = fmaxf(mx, __shfl_xor(mx, 2));
    mx = fmaxf(mx, __shfl_xor(mx, 4));
    float p = __expf(s - mx);
    float su = p;
    su += __shfl_xor(su, 1);
    su += __shfl_xor(su, 2);
    su += __shfl_xor(su, 4);
    ps[tq][tk] = p / su;
    __syncthreads();
#pragma unroll
    for (int t2 = 0; t2 < 8; t2++) {
        float o = 0.f;
#pragma unroll
        for (int k2 = 0; k2 < 8; k2++) o += ps[t2][k2] * vs[k2][d];
        out[(size_t)(t2 * 1568 + b) * 1024 + h * 64 + d] = f2bf(o);
    }
}

// ---------------------------------------------------------------------------
// Spatial attention, MFMA version.  S'=197 (13 q-tiles of 16, 13 k-tiles),
// one block(256)=4 waves per (u=t*8+n, h).
// ---------------------------------------------------------------------------
#define KLS 72
#define PVS 232
__global__ __launch_bounds__(256) void attn_s(const u16* __restrict__ qkv,
                                              const float* __restrict__ rpb,
                                              u16* __restrict__ out) {
    __shared__ u16 Kl[208 * KLS];        // [key][feat], rows 197..207 zero
    __shared__ u16 Vt[64 * PVS];         // [feat][key], cols 197..231 zero
    __shared__ u16 Pl[4][16 * PVS];      // per-wave P tile [qlocal][key]
    __shared__ float rpb_l[736];
    int blk = blockIdx.x;
    int u = blk & 63, h = blk >> 6;
    int tid = threadIdx.x;
    int w = tid >> 6, lane = tid & 63;
    int lm = lane & 15, quad = lane >> 4;

    // ---- stage K, V^T ----
    for (int idx = tid; idx < 197 * 8; idx += 256) {
        int s = idx >> 3, c8 = idx & 7;
        const u16* gp = qkv + (size_t)(s * 64 + u) * 3072 + h * 64 + c8 * 8;
        uint4 kv = *(const uint4*)(gp + 1024);
        uint4 vv = *(const uint4*)(gp + 2048);
        *(uint4*)&Kl[s * KLS + c8 * 8] = kv;
        const u16* vp = (const u16*)&vv;
#pragma unroll
        for (int j = 0; j < 8; j++) Vt[(c8 * 8 + j) * PVS + s] = vp[j];
    }
    for (int i = tid; i < 11 * KLS; i += 256) Kl[197 * KLS + i] = 0;
    for (int i = tid; i < 64 * 35; i += 256) {
        int dd = i / 35, c = 197 + (i - dd * 35);
        Vt[dd * PVS + c] = 0;
    }
    { // zero P pad cols 208..223 (never rewritten)
        for (int i = lane; i < 256; i += 64) {
            int r = i >> 4, c = 208 + (i & 15);
            Pl[w][r * PVS + c] = 0;
        }
    }
    for (int i = tid; i < 729; i += 256) rpb_l[i] = rpb[i * 16 + h];
    __syncthreads();

    for (int it = 0; it < 4; it++) {
        int qt = it * 4 + w;
        bool act = qt < 13;
        f32x4 sc[13];
        float rs[4];
        if (act) {
            // Q A-frags straight from global: A[m=lm][k=quad*8+j]
            int qrow = qt * 16 + lm;
            int srq = qrow > 196 ? 196 : qrow;
            const u16* qp = qkv + (size_t)(srq * 64 + u) * 3072 + h * 64 + quad * 8;
            bf16x8 aq0 = *(const bf16x8*)qp;
            bf16x8 aq1 = *(const bf16x8*)(qp + 32);
            for (int kt = 0; kt < 13; kt++) {
                bf16x8 bk0 = *(const bf16x8*)&Kl[(kt * 16 + lm) * KLS + quad * 8];
                bf16x8 bk1 = *(const bf16x8*)&Kl[(kt * 16 + lm) * KLS + 32 + quad * 8];
                f32x4 s = __builtin_amdgcn_mfma_f32_16x16x32_bf16(aq0, bk0, (f32x4){0.f, 0.f, 0.f, 0.f}, 0, 0, 0);
                sc[kt] = __builtin_amdgcn_mfma_f32_16x16x32_bf16(aq1, bk1, s, 0, 0, 0);
            }
            int tk = lm;
#pragma unroll
            for (int r = 0; r < 4; r++) {
                int qr = qt * 16 + quad * 4 + r;
                int qcl = qr > 196 ? 196 : qr;
                int lq = qcl - 1;
                int qi = lq / 14, qj = lq - qi * 14;
                for (int kt = 0; kt < 13; kt++) {
                    int tkk = kt * 16 + tk;
                    float v;
                    if (tkk >= 197) v = -1e30f;
                    else {
                        v = sc[kt][r] * 0.125f;
                        if (qr >= 1 && tkk >= 1) {
                            int lk = tkk - 1;
                            int ki = lk / 14, kj = lk - ki * 14;
                            v += rpb_l[(qi - ki + 13) * 27 + (qj - kj + 13)];
                        }
                    }
                    sc[kt][r] = v;
                }
                float mx = -3e38f;
                for (int kt = 0; kt < 13; kt++) mx = fmaxf(mx, sc[kt][r]);
                mx = fmaxf(mx, __shfl_xor(mx, 1));
                mx = fmaxf(mx, __shfl_xor(mx, 2));
                mx = fmaxf(mx, __shfl_xor(mx, 4));
                mx = fmaxf(mx, __shfl_xor(mx, 8));
                float sm = 0.f;
                for (int kt = 0; kt < 13; kt++) {
                    float p = __expf(sc[kt][r] - mx);
                    sc[kt][r] = p;
                    sm += p;
                }
                sm += __shfl_xor(sm, 1);
                sm += __shfl_xor(sm, 2);
                sm += __shfl_xor(sm, 4);
                sm += __shfl_xor(sm, 8);
                rs[r] = sm;
                for (int kt = 0; kt < 13; kt++)
                    Pl[w][(quad * 4 + r) * PVS + kt * 16 + tk] = f2bf(sc[kt][r]);
            }
        }
        __syncthreads();
        if (act) {
            bf16x8 pa[7];
#pragma unroll
            for (int kc = 0; kc < 7; kc++)
                pa[kc] = *(const bf16x8*)&Pl[w][lm * PVS + kc * 32 + quad * 8];
#pragma unroll
            for (int ct = 0; ct < 4; ct++) {
                f32x4 o = (f32x4){0.f, 0.f, 0.f, 0.f};
#pragma unroll
                for (int kc = 0; kc < 7; kc++) {
                    bf16x8 vb = *(const bf16x8*)&Vt[(ct * 16 + lm) * PVS + kc * 32 + quad * 8];
                    o = __builtin_amdgcn_mfma_f32_16x16x32_bf16(pa[kc], vb, o, 0, 0, 0);
                }
#pragma unroll
                for (int r = 0; r < 4; r++) {
                    int qr = qt * 16 + quad * 4 + r;
                    if (qr < 197)
                        out[(size_t)(qr * 64 + u) * 1024 + h * 64 + ct * 16 + lm] =
                            f2bf(o[r] / rs[r]);
                }
            }
        }
        __syncthreads();
    }
}

// ---------------------------------------------------------------------------
// Residual adds (float4 vectorized)
// ---------------------------------------------------------------------------
__global__ __launch_bounds__(256) void add_cls(const u16* __restrict__ R, float4* __restrict__ resid4) {
    int tid = blockIdx.x * 256 + threadIdx.x;   // 2048
    int c4 = tid & 255, n = tid >> 8;
    float s0 = 0.f, s1 = 0.f, s2 = 0.f, s3 = 0.f;
#pragma unroll
    for (int t = 0; t < 8; t++) {
        ushort4 rv = *(const ushort4*)&R[(size_t)(t * 8 + n) * 1024 + c4 * 4];
        s0 += bf2f(rv.x); s1 += bf2f(rv.y); s2 += bf2f(rv.z); s3 += bf2f(rv.w);
    }
    float4 v = resid4[tid];
    v.x += s0 * 0.125f; v.y += s1 * 0.125f; v.z += s2 * 0.125f; v.w += s3 * 0.125f;
    resid4[tid] = v;
}

__global__ __launch_bounds__(256) void add_spa(const u16* __restrict__ R, float4* __restrict__ resid4) {
    int tid = blockIdx.x * 256 + threadIdx.x;   // 1568*2048
    int c4 = tid & 255;
    int n = (tid >> 8) & 7;
    int r = tid >> 11;
    int t = r & 7, l = r >> 3;
    int srow = (l + 1) * 64 + t * 8 + n;
    ushort4 rv = *(const ushort4*)&R[(size_t)srow * 1024 + c4 * 4];
    float4 v = resid4[tid + 2048];
    v.x += bf2f(rv.x); v.y += bf2f(rv.y); v.z += bf2f(rv.z); v.w += bf2f(rv.w);
    resid4[tid + 2048] = v;
}

__global__ __launch_bounds__(256) void add_flat(const ushort4* __restrict__ R4, float4* __restrict__ resid4) {
    int tid = blockIdx.x * 256 + threadIdx.x;   // 12552*256
    ushort4 rv = R4[tid];
    float4 v = resid4[tid];
    v.x += bf2f(rv.x); v.y += bf2f(rv.y); v.z += bf2f(rv.z); v.w += bf2f(rv.w);
    resid4[tid] = v;
}

// ---------------------------------------------------------------------------
extern "C" void kernel_launch(void* const* d_in, const int* in_sizes, int n_in,
                              void* d_out, int out_size, void* d_ws, size_t ws_size,
                              hipStream_t stream) {
    const float* x      = (const float*)d_in[0];
    const float* pos_w  = (const float*)d_in[1];
    const float* pos_b  = (const float*)d_in[2];
    const float* ln_t_g = (const float*)d_in[3];
    const float* ln_t_b = (const float*)d_in[4];
    const float* rpb_t  = (const float*)d_in[5];
    const float* wqkv_t = (const float*)d_in[6];
    const float* bqkv_t = (const float*)d_in[7];
    const float* wo_t   = (const float*)d_in[8];
    const float* bo_t   = (const float*)d_in[9];
    const float* ln1_g  = (const float*)d_in[10];
    const float* ln1_b  = (const float*)d_in[11];
    const float* rpb_s  = (const float*)d_in[12];
    const float* wqkv_s = (const float*)d_in[13];
    const float* bqkv_s = (const float*)d_in[14];
    const float* wo_s   = (const float*)d_in[15];
    const float* bo_s   = (const float*)d_in[16];
    const float* ln2_g  = (const float*)d_in[17];
    const float* ln2_b  = (const float*)d_in[18];
    const float* fc_w   = (const float*)d_in[19];
    const float* fc_b   = (const float*)d_in[20];
    const float* proj_w = (const float*)d_in[21];
    const float* proj_b = (const float*)d_in[22];
    float* resid = (float*)d_out;

    // workspace arena (bf16 elements)
    u16* Wq_t  = (u16*)d_ws;
    u16* Wo_t  = Wq_t + 3145728;
    u16* Wq_s  = Wo_t + 1048576;
    u16* Wo_s  = Wq_s + 3145728;
    u16* Wfc   = Wo_s + 1048576;
    u16* Wpj   = Wfc  + 4194304;
    u16* Albuf = Wpj  + 4194304;          // 12608*1024
    u16* QKV   = Albuf + 12910592;        // 12608*3072
    u16* Obuf  = QKV   + 38731776;        // 12608*1024
    u16* Rbuf  = Obuf  + 12910592;        // 12608*1024
    u16* Hbuf  = QKV;                     // alias: 12552*4096 fits in QKV+Obuf
    float* wt  = (float*)QKV;             // alias: 27*1024 f32, used only by posembed

    // weight conversion
    cvt_bf16<<<3072, 256, 0, stream>>>((const float4*)wqkv_t, (ushort4*)Wq_t, 786432);
    cvt_bf16<<<1024, 256, 0, stream>>>((const float4*)wo_t,   (ushort4*)Wo_t, 262144);
    cvt_bf16<<<3072, 256, 0, stream>>>((const float4*)wqkv_s, (ushort4*)Wq_s, 786432);
    cvt_bf16<<<1024, 256, 0, stream>>>((const float4*)wo_s,   (ushort4*)Wo_s, 262144);
    cvt_bf16<<<4096, 256, 0, stream>>>((const float4*)fc_w,   (ushort4*)Wfc,  1048576);
    cvt_bf16<<<4096, 256, 0, stream>>>((const float4*)proj_w, (ushort4*)Wpj,  1048576);
    cvt_wt<<<108, 256, 0, stream>>>(pos_w, wt);

    // positional embedding -> resid (= xpe)
    posembed<<<12552, 256, 0, stream>>>((const float4*)x, (const float4*)wt,
                                        (const float4*)pos_b, (float4*)resid);

    // temporal attention (result NOT added to resid; feeds spatial LN only)
    ln_kernel<<<12544, 256, 0, stream>>>(resid, nullptr, ln_t_g, ln_t_b, Albuf, 0);
    gemm_bf16<<<2352, 256, 0, stream>>>(Albuf, Wq_t, bqkv_t, QKV, 12544, 3072, 1024, 0, 24);
    attn_t<<<25088, 64, 0, stream>>>(QKV, rpb_t, Obuf);
    gemm_bf16<<<784, 256, 0, stream>>>(Obuf, Wo_t, bo_t, Rbuf, 12544, 1024, 1024, 0, 8);

    // spatial attention (LN1 fuses xt_full = xpe + rt gather)
    ln_kernel<<<12608, 256, 0, stream>>>(resid, Rbuf, ln1_g, ln1_b, Albuf, 1);
    gemm_bf16<<<2376, 256, 0, stream>>>(Albuf, Wq_s, bqkv_s, QKV, 12608, 3072, 1024, 0, 24);
    attn_s<<<1024, 256, 0, stream>>>(QKV, rpb_s, Obuf);
    gemm_bf16<<<792, 256, 0, stream>>>(Obuf, Wo_s, bo_s, Rbuf, 12608, 1024, 1024, 0, 8);
    add_cls<<<8, 256, 0, stream>>>(Rbuf, (float4*)resid);
    add_spa<<<12544, 256, 0, stream>>>(Rbuf, (float4*)resid);

    // MLP with QuickGELU
    ln_kernel<<<12552, 256, 0, stream>>>(resid, nullptr, ln2_g, ln2_b, Albuf, 2);
    gemm_bf16<<<3168, 256, 0, stream>>>(Albuf, Wfc, fc_b, Hbuf, 12552, 4096, 1024, 1, 32);
    gemm_bf16<<<792, 256, 0, stream>>>(Hbuf, Wpj, proj_b, Rbuf, 12552, 1024, 4096, 0, 8);
    add_flat<<<12552, 256, 0, stream>>>((const ushort4*)Rbuf, (float4*)resid);
}